// Round 6
// baseline (33.968 us; speedup 1.0000x reference)
//
#include <hip/hip_runtime.h>
#include <cmath>

// KFIoU loss: pred (NP x 5), target (NT x 5) -> loss (NP x NT) f32.
//
// Numerics (established R1-R5): the harness's "np" reference is a FLOAT32
// numpy evaluation of the cancellation-heavy Sigma = P - K*P chain. We must
// reproduce its fp32 noise bit-for-bit: identical op order, no fma
// contraction, correctly-rounded f32 div/sqrt (__fdiv_rn/__fsqrt_rn), and
// correctly-rounded f32 sin/cos (evaluated in double, rounded to f32).
// R5 passed at absmax 0.0117 with this recipe.
//
// Perf structure (this round): split the fp64-sincos box-param computation
// into a tiny precompute kernel writing d_ws (6144 boxes, once), so the hot
// pair kernel carries no fp64 code (low VGPR), no LDS, no syncthreads, and
// 2x the wave occupancy (ROWS=16 -> 2048 blocks = 8 waves/SIMD).

constexpr int ROWS = 16;   // pred rows per block tile
constexpr int COLS = 256;  // target cols per block tile

// ---------------- kernel A: per-box params (s00, s01, s11, Vb) ------------
__global__ __launch_bounds__(256) void box_param_kernel(
    const float* __restrict__ pred, int np,
    const float* __restrict__ target, int nt,
    float4* __restrict__ ws) {
#pragma clang fp contract(off)
  int i = blockIdx.x * 256 + threadIdx.x;
  int n = np + nt;
  if (i >= n) return;
  const float* bx = (i < np) ? (pred + (size_t)i * 5)
                             : (target + (size_t)(i - np) * 5);
  float w = fminf(fmaxf(bx[2], 1e-7f), 1e7f);
  float h = fminf(fmaxf(bx[3], 1e-7f), 1e7f);
  float r = bx[4];
  // correctly-rounded f32 sin/cos via double evaluation (matches numpy)
  float s = (float)sin((double)r);
  float c = (float)cos((double)r);
  float a = (0.5f * w) * (0.5f * w);
  float b = (0.5f * h) * (0.5f * h);
  float s00 = a * c * c + b * s * s;
  float s01 = (a - b) * s * c;
  float s11 = a * s * s + b * c * c;
  float det = s00 * s11 - s01 * s01;
  float vb  = 4.0f * __fsqrt_rn(fabsf(det));
  ws[i] = make_float4(s00, s01, s11, vb);
}

// ---------------- kernel B: pair loss (no fp64, no LDS) -------------------
__device__ __forceinline__ float kf_pair(float4 p, float4 t) {
#pragma clang fp contract(off)
  float m00 = p.x + t.x;
  float m01 = p.y + t.y;
  float m11 = p.z + t.z;
  float det_m = m00 * m11 - m01 * m01;
  float i00 = __fdiv_rn(m11, det_m);
  float i01 = __fdiv_rn(-m01, det_m);
  float i11 = __fdiv_rn(m00, det_m);
  float k00 = p.x * i00 + p.y * i01;
  float k01 = p.x * i01 + p.y * i11;
  float k10 = p.y * i00 + p.z * i01;
  float k11 = p.y * i01 + p.z * i11;
  float sig00 = p.x - (k00 * p.x + k01 * p.y);
  float sig01 = p.y - (k00 * p.y + k01 * p.z);
  float sig10 = p.y - (k10 * p.x + k11 * p.y);
  float sig11 = p.z - (k10 * p.y + k11 * p.z);
  float det_sig = sig00 * sig11 - sig01 * sig10;
  float vb = 4.0f * __fsqrt_rn(fabsf(det_sig));
  float denom = p.w + t.w - vb + 1e-6f;
  float kf = __fdiv_rn(vb, denom);
  return fmaxf(1.0f - kf, 0.0f);
}

__global__ __launch_bounds__(256) void kf_loss_kernel(
    const float4* __restrict__ pp,   // np pred params
    const float4* __restrict__ tp,   // nt target params
    float* __restrict__ out, int np, int nt) {
  const int tid  = threadIdx.x;
  const int row0 = blockIdx.x * ROWS;
  const int col0 = blockIdx.y * COLS;

  const int lane = tid & 63;   // wave = 64 lanes on CDNA
  const int wv   = tid >> 6;   // 4 waves per block
  const int jc   = lane * 4;   // col offset within tile (0..252)
  const int col  = col0 + jc;

  // 4 target param sets per lane: contiguous 64B/lane -> coalesced, L2-hit.
  float4 t0, t1, t2, t3;
  if (col + 3 < nt) {
    t0 = tp[col + 0]; t1 = tp[col + 1]; t2 = tp[col + 2]; t3 = tp[col + 3];
  } else {
    t0 = t1 = t2 = t3 = make_float4(1.f, 0.f, 1.f, 4.f);
    if (col + 0 < nt) t0 = tp[col + 0];
    if (col + 1 < nt) t1 = tp[col + 1];
    if (col + 2 < nt) t2 = tp[col + 2];
    if (col + 3 < nt) t3 = tp[col + 3];
  }

  for (int rr = wv; rr < ROWS; rr += 4) {
    int row = row0 + rr;
    if (row >= np) break;
    float4 pv = pp[row];         // wave-uniform broadcast load (L1-hit)
    float4 o;
    o.x = kf_pair(pv, t0);
    o.y = kf_pair(pv, t1);
    o.z = kf_pair(pv, t2);
    o.w = kf_pair(pv, t3);
    size_t base = (size_t)row * (size_t)nt + (size_t)col;
    if (col + 3 < nt) {
      *reinterpret_cast<float4*>(out + base) = o;  // coalesced 16B store
    } else {
      float tmp[4] = {o.x, o.y, o.z, o.w};
      for (int q = 0; q < 4; ++q)
        if (col + q < nt) out[base + q] = tmp[q];
    }
  }
}

extern "C" void kernel_launch(void* const* d_in, const int* in_sizes, int n_in,
                              void* d_out, int out_size, void* d_ws, size_t ws_size,
                              hipStream_t stream) {
  const float* pred   = (const float*)d_in[0];
  const float* target = (const float*)d_in[1];
  float* out = (float*)d_out;
  int np = in_sizes[0] / 5;
  int nt = in_sizes[1] / 5;

  float4* params = (float4*)d_ws;           // np + nt entries
  int nbox = np + nt;
  box_param_kernel<<<(nbox + 255) / 256, 256, 0, stream>>>(
      pred, np, target, nt, params);

  dim3 grid((np + ROWS - 1) / ROWS, (nt + COLS - 1) / COLS);
  kf_loss_kernel<<<grid, dim3(256), 0, stream>>>(
      params, params + np, out, np, nt);
}

// Round 7
// 33.728 us; speedup vs baseline: 1.0071x; 1.0071x over previous
//
#include <hip/hip_runtime.h>
#include <cmath>

// KFIoU loss: pred (NP x 5), target (NT x 5) -> loss (NP x NT) f32.
//
// Numerics (established R1-R5): the harness's "np" reference is a FLOAT32
// numpy evaluation of the cancellation-heavy Sigma = P - K*P chain. We
// reproduce its fp32 noise bit-for-bit: identical op order, no fma
// contraction, correctly-rounded f32 div/sqrt (__fdiv_rn/__fsqrt_rn), and
// correctly-rounded f32 sin/cos (evaluated in double, rounded to f32).
// R5 passed at absmax 0.0117 with this recipe. Pair math is UNTOUCHED here.
//
// Perf (this round): occupancy-first restructure. Each thread owns ONE
// target column (4 VGPR of t-params), loops 16 pred rows, unroll-2 for ILP
// (CR-divide chains serialize on VCC, so TLP must hide latency ->
// __launch_bounds__(256,8) pins <=64 VGPR = 8 waves/SIMD; 2048 blocks =
// 8 blocks/CU, all resident in one dispatch round).

constexpr int ROWS = 16;   // pred rows per block tile
constexpr int COLS = 256;  // target cols per block (= blockDim.x)

// ---------------- kernel A: per-box params (s00, s01, s11, Vb) ------------
__global__ __launch_bounds__(256) void box_param_kernel(
    const float* __restrict__ pred, int np,
    const float* __restrict__ target, int nt,
    float4* __restrict__ ws) {
#pragma clang fp contract(off)
  int i = blockIdx.x * 256 + threadIdx.x;
  int n = np + nt;
  if (i >= n) return;
  const float* bx = (i < np) ? (pred + (size_t)i * 5)
                             : (target + (size_t)(i - np) * 5);
  float w = fminf(fmaxf(bx[2], 1e-7f), 1e7f);
  float h = fminf(fmaxf(bx[3], 1e-7f), 1e7f);
  float r = bx[4];
  // correctly-rounded f32 sin/cos via double evaluation (matches numpy)
  float s = (float)sin((double)r);
  float c = (float)cos((double)r);
  float a = (0.5f * w) * (0.5f * w);
  float b = (0.5f * h) * (0.5f * h);
  float s00 = a * c * c + b * s * s;
  float s01 = (a - b) * s * c;
  float s11 = a * s * s + b * c * c;
  float det = s00 * s11 - s01 * s01;
  float vb  = 4.0f * __fsqrt_rn(fabsf(det));
  ws[i] = make_float4(s00, s01, s11, vb);
}

// ---------------- kernel B: pair loss (no fp64, no LDS) -------------------
__device__ __forceinline__ float kf_pair(float4 p, float4 t) {
#pragma clang fp contract(off)
  float m00 = p.x + t.x;
  float m01 = p.y + t.y;
  float m11 = p.z + t.z;
  float det_m = m00 * m11 - m01 * m01;
  float i00 = __fdiv_rn(m11, det_m);
  float i01 = __fdiv_rn(-m01, det_m);
  float i11 = __fdiv_rn(m00, det_m);
  float k00 = p.x * i00 + p.y * i01;
  float k01 = p.x * i01 + p.y * i11;
  float k10 = p.y * i00 + p.z * i01;
  float k11 = p.y * i01 + p.z * i11;
  float sig00 = p.x - (k00 * p.x + k01 * p.y);
  float sig01 = p.y - (k00 * p.y + k01 * p.z);
  float sig10 = p.y - (k10 * p.x + k11 * p.y);
  float sig11 = p.z - (k10 * p.y + k11 * p.z);
  float det_sig = sig00 * sig11 - sig01 * sig10;
  float vb = 4.0f * __fsqrt_rn(fabsf(det_sig));
  float denom = p.w + t.w - vb + 1e-6f;
  float kf = __fdiv_rn(vb, denom);
  return fmaxf(1.0f - kf, 0.0f);
}

__global__ __launch_bounds__(256, 8) void kf_loss_kernel(
    const float4* __restrict__ pp,   // np pred params
    const float4* __restrict__ tp,   // nt target params
    float* __restrict__ out, int np, int nt) {
  const int col  = blockIdx.y * COLS + threadIdx.x;
  const int row0 = blockIdx.x * ROWS;
  if (col >= nt) return;

  const float4 t = tp[col];          // 4 VGPR, held for the whole kernel

  // 16 rows, unroll-2: two independent CR-divide chains in flight.
  #pragma unroll
  for (int rr = 0; rr < ROWS; rr += 2) {
    int r0 = row0 + rr;
    int r1 = r0 + 1;
    int r0c = (r0 < np) ? r0 : (np - 1);   // clamp (np%ROWS==0 in practice)
    int r1c = (r1 < np) ? r1 : (np - 1);
    float4 p0 = pp[r0c];               // wave-uniform -> scalar loads
    float4 p1 = pp[r1c];
    float o0 = kf_pair(p0, t);
    float o1 = kf_pair(p1, t);
    if (r0 < np) out[(size_t)r0 * (size_t)nt + col] = o0;
    if (r1 < np) out[(size_t)r1 * (size_t)nt + col] = o1;
  }
}

extern "C" void kernel_launch(void* const* d_in, const int* in_sizes, int n_in,
                              void* d_out, int out_size, void* d_ws, size_t ws_size,
                              hipStream_t stream) {
  const float* pred   = (const float*)d_in[0];
  const float* target = (const float*)d_in[1];
  float* out = (float*)d_out;
  int np = in_sizes[0] / 5;
  int nt = in_sizes[1] / 5;

  float4* params = (float4*)d_ws;           // np + nt entries
  int nbox = np + nt;
  box_param_kernel<<<(nbox + 255) / 256, 256, 0, stream>>>(
      pred, np, target, nt, params);

  dim3 grid((np + ROWS - 1) / ROWS, (nt + COLS - 1) / COLS);
  kf_loss_kernel<<<grid, dim3(COLS), 0, stream>>>(
      params, params + np, out, np, nt);
}

// Round 8
// 31.581 us; speedup vs baseline: 1.0756x; 1.0680x over previous
//
#include <hip/hip_runtime.h>
#include <cmath>

// KFIoU loss: pred (NP x 5), target (NT x 5) -> loss (NP x NT) f32.
//
// Numerics (established R1-R5): the harness's "np" reference is a FLOAT32
// numpy evaluation of the cancellation-heavy Sigma = P - K*P chain. We
// reproduce its fp32 noise bit-for-bit: identical op order, no fma
// contraction, correctly-rounded f32 div/sqrt (__fdiv_rn/__fsqrt_rn),
// correctly-rounded f32 sin/cos (evaluated in double, rounded to f32).
// R5 passed at absmax 0.0117; R6/R7 confirmed the pair kernel is pure
// issue-bound (~32 us invariant across memory structures).
//
// Perf (this round): packed FP32. v_pk_add_f32 / v_pk_mul_f32 are
// full-rate on CDNA4 and IEEE-identical per half -> process 2 pred rows as
// the halves of an ext_vector(2) float. Halves the no-contract mul/add
// stream (~40 -> ~20 instrs/pair-equiv); divides/sqrt stay scalar but the
// two halves' chains are independent (ILP). Bit-identical results.

typedef float v2f __attribute__((ext_vector_type(2)));

constexpr int ROWS = 16;   // pred rows per block tile (2 per iteration)
constexpr int COLS = 256;  // target cols per block (= blockDim.x)

// ---------------- kernel A: per-box params (s00, s01, s11, Vb) ------------
__global__ __launch_bounds__(256) void box_param_kernel(
    const float* __restrict__ pred, int np,
    const float* __restrict__ target, int nt,
    float4* __restrict__ ws) {
#pragma clang fp contract(off)
  int i = blockIdx.x * 256 + threadIdx.x;
  int n = np + nt;
  if (i >= n) return;
  const float* bx = (i < np) ? (pred + (size_t)i * 5)
                             : (target + (size_t)(i - np) * 5);
  float w = fminf(fmaxf(bx[2], 1e-7f), 1e7f);
  float h = fminf(fmaxf(bx[3], 1e-7f), 1e7f);
  float r = bx[4];
  // correctly-rounded f32 sin/cos via double evaluation (matches numpy)
  float s = (float)sin((double)r);
  float c = (float)cos((double)r);
  float a = (0.5f * w) * (0.5f * w);
  float b = (0.5f * h) * (0.5f * h);
  float s00 = a * c * c + b * s * s;
  float s01 = (a - b) * s * c;
  float s11 = a * s * s + b * c * c;
  float det = s00 * s11 - s01 * s01;
  float vb  = 4.0f * __fsqrt_rn(fabsf(det));
  ws[i] = make_float4(s00, s01, s11, vb);
}

// ---------------- kernel B: pair loss, 2 rows per call (packed f32) -------
__device__ __forceinline__ v2f kf_pair2(float4 p0, float4 p1, float4 t) {
#pragma clang fp contract(off)
  v2f px = {p0.x, p1.x};
  v2f py = {p0.y, p1.y};
  v2f pz = {p0.z, p1.z};
  v2f pw = {p0.w, p1.w};

  v2f m00 = px + t.x;            // scalar splats across both halves
  v2f m01 = py + t.y;
  v2f m11 = pz + t.z;
  v2f det_m = m00 * m11 - m01 * m01;

  v2f i00, i01, i11;
  i00[0] = __fdiv_rn(m11[0], det_m[0]);
  i00[1] = __fdiv_rn(m11[1], det_m[1]);
  i01[0] = __fdiv_rn(-m01[0], det_m[0]);
  i01[1] = __fdiv_rn(-m01[1], det_m[1]);
  i11[0] = __fdiv_rn(m00[0], det_m[0]);
  i11[1] = __fdiv_rn(m00[1], det_m[1]);

  v2f k00 = px * i00 + py * i01;
  v2f k01 = px * i01 + py * i11;
  v2f k10 = py * i00 + pz * i01;
  v2f k11 = py * i01 + pz * i11;

  v2f sig00 = px - (k00 * px + k01 * py);
  v2f sig01 = py - (k00 * py + k01 * pz);
  v2f sig10 = py - (k10 * px + k11 * py);
  v2f sig11 = pz - (k10 * py + k11 * pz);

  v2f det_sig = sig00 * sig11 - sig01 * sig10;
  v2f vb;
  vb[0] = 4.0f * __fsqrt_rn(fabsf(det_sig[0]));
  vb[1] = 4.0f * __fsqrt_rn(fabsf(det_sig[1]));

  v2f denom = pw + t.w - vb + 1e-6f;    // ((pw+tw)-vb)+eps, left-assoc
  v2f kf;
  kf[0] = __fdiv_rn(vb[0], denom[0]);
  kf[1] = __fdiv_rn(vb[1], denom[1]);

  v2f res;
  res[0] = fmaxf(1.0f - kf[0], 0.0f);
  res[1] = fmaxf(1.0f - kf[1], 0.0f);
  return res;
}

__global__ __launch_bounds__(256, 8) void kf_loss_kernel(
    const float4* __restrict__ pp,   // np pred params
    const float4* __restrict__ tp,   // nt target params
    float* __restrict__ out, int np, int nt) {
  const int col  = blockIdx.y * COLS + threadIdx.x;
  const int row0 = blockIdx.x * ROWS;
  if (col >= nt) return;

  const float4 t = tp[col];          // 4 VGPR, held for the whole kernel

  for (int rr = 0; rr < ROWS; rr += 2) {
    int r0 = row0 + rr;
    int r1 = r0 + 1;
    int r0c = (r0 < np) ? r0 : (np - 1);
    int r1c = (r1 < np) ? r1 : (np - 1);
    float4 p0 = pp[r0c];             // wave-uniform -> scalar loads
    float4 p1 = pp[r1c];
    v2f o = kf_pair2(p0, p1, t);
    if (r0 < np) out[(size_t)r0 * (size_t)nt + col] = o[0];
    if (r1 < np) out[(size_t)r1 * (size_t)nt + col] = o[1];
  }
}

extern "C" void kernel_launch(void* const* d_in, const int* in_sizes, int n_in,
                              void* d_out, int out_size, void* d_ws, size_t ws_size,
                              hipStream_t stream) {
  const float* pred   = (const float*)d_in[0];
  const float* target = (const float*)d_in[1];
  float* out = (float*)d_out;
  int np = in_sizes[0] / 5;
  int nt = in_sizes[1] / 5;

  float4* params = (float4*)d_ws;           // np + nt entries
  int nbox = np + nt;
  box_param_kernel<<<(nbox + 255) / 256, 256, 0, stream>>>(
      pred, np, target, nt, params);

  dim3 grid((np + ROWS - 1) / ROWS, (nt + COLS - 1) / COLS);
  kf_loss_kernel<<<grid, dim3(COLS), 0, stream>>>(
      params, params + np, out, np, nt);
}